// Round 3
// baseline (300.694 us; speedup 1.0000x reference)
//
#include <hip/hip_runtime.h>

typedef __attribute__((ext_vector_type(8))) short bf16x8;
typedef __attribute__((ext_vector_type(4))) short bf16x4;
typedef __attribute__((ext_vector_type(4))) float f32x4;

__device__ __forceinline__ unsigned short f2bf(float x){
  unsigned u = __float_as_uint(x);
  u = (u + 0x7fffu + ((u >> 16) & 1u)) >> 16;
  return (unsigned short)u;
}

// ---------------- Bjorck (polar factor) small kernels ----------------

__global__ __launch_bounds__(256) void knorm(const float* __restrict__ wt, float* __restrict__ n2){
  int t = blockIdx.x * 256 + threadIdx.x;
  float4 v = reinterpret_cast<const float4*>(wt)[t];
  float s = v.x*v.x + v.y*v.y + v.z*v.z + v.w*v.w;
  #pragma unroll
  for (int o = 32; o > 0; o >>= 1) s += __shfl_down(s, o, 64);
  __shared__ float red[4];
  if ((threadIdx.x & 63) == 0) red[threadIdx.x >> 6] = s;
  __syncthreads();
  if (threadIdx.x == 0) atomicAdd(n2, red[0] + red[1] + red[2] + red[3]);
}

__global__ __launch_bounds__(256) void kinit(const float* __restrict__ wt, const float* __restrict__ n2,
                                             float* __restrict__ W){
  int c = blockIdx.x;
  int r = threadIdx.x;
  float s = rsqrtf(*n2) * (1.0f / 0.3f);
  W[(size_t)r * 256 + c]         = wt[(size_t)c * 512 + r] * s;
  W[(size_t)(r + 256) * 256 + c] = wt[(size_t)c * 512 + r + 256] * s;
}

// G += partial(W^T W): grid (8 j, 8 i, 8 k-parts), 32x32 tile, k-range 64
__global__ __launch_bounds__(256) void kgram2(const float* __restrict__ W, float* __restrict__ G){
  __shared__ __align__(16) float Wi[64][32];
  __shared__ __align__(16) float Wj[64][32];
  const int t = threadIdx.x;
  const int i0 = blockIdx.y * 32, j0 = blockIdx.x * 32, k0 = blockIdx.z * 64;
  const int lr = t >> 3, lc = (t & 7) * 4;
  #pragma unroll
  for (int p = 0; p < 2; ++p){
    int r = lr + p * 32;
    *reinterpret_cast<float4*>(&Wi[r][lc]) =
        *reinterpret_cast<const float4*>(&W[(size_t)(k0 + r) * 256 + i0 + lc]);
    *reinterpret_cast<float4*>(&Wj[r][lc]) =
        *reinterpret_cast<const float4*>(&W[(size_t)(k0 + r) * 256 + j0 + lc]);
  }
  __syncthreads();
  const int tx = t & 31, iy = t >> 5;
  float g0 = 0, g1 = 0, g2 = 0, g3 = 0;
  #pragma unroll 8
  for (int k = 0; k < 64; ++k){
    float wj = Wj[k][tx];
    float4 wi = *reinterpret_cast<const float4*>(&Wi[k][iy * 4]);
    g0 = fmaf(wi.x, wj, g0); g1 = fmaf(wi.y, wj, g1);
    g2 = fmaf(wi.z, wj, g2); g3 = fmaf(wi.w, wj, g3);
  }
  float* gp = &G[(size_t)(i0 + iy * 4) * 256 + j0 + tx];
  atomicAdd(gp,       g0); atomicAdd(gp + 256, g1);
  atomicAdd(gp + 512, g2); atomicAdd(gp + 768, g3);
}

// W <- ca*W + cb*(W G) + cc*(W G) G ; zeroes Gnext; last: emit k-tiled bf16 WT2
__global__ __launch_bounds__(512) void kupdate2(float* __restrict__ W, const float* __restrict__ G,
    float* __restrict__ Gnext, float ca, float cb, float cc, int last,
    unsigned short* __restrict__ WT2){
  __shared__ float wr[2][256], yl[2][256];
  const int t = threadIdx.x;
  const int c = t & 255, row = t >> 8;
  const int r = blockIdx.x * 2 + row;
  wr[row][c] = W[(size_t)r * 256 + c];
  __syncthreads();
  float y = 0;
  #pragma unroll 8
  for (int k = 0; k < 256; ++k)
    y = fmaf(wr[row][k], G[(size_t)k * 256 + c], y);
  yl[row][c] = y;
  __syncthreads();
  float d = 0;
  #pragma unroll 8
  for (int k = 0; k < 256; ++k)
    d = fmaf(yl[row][k], G[(size_t)k * 256 + c], d);
  float nw = ca * wr[row][c] + cb * y + cc * d;
  W[(size_t)r * 256 + c] = nw;
  if (r < 256) Gnext[(size_t)r * 256 + c] = 0.0f;
  if (last) WT2[((size_t)(r >> 3) * 256 + c) * 8 + (r & 7)] = f2bf(nw);
}

// ---------------- barrier-free GEMM: C[M,256] = A[M,KDIM](f32) * B(bf16 k-tiled) ----
// B layout: element (k, c) at ((k/8)*256 + c)*8 + k%8
// Each wave loads its own A fragments directly from global (no LDS, no syncs).
// EPI==0: bf16 k-tiled output (KS must be 1)
// EPI==1: fp32 partial per kp -> Cout + kp*M*256 (plain stores)

template<int KDIM, int KS, int EPI>
__global__ __launch_bounds__(256) void kgemm2(const float* __restrict__ A,
    const unsigned short* __restrict__ B, void* __restrict__ Cout){
  const int t = threadIdx.x;
  const int wave = t >> 6, lane = t & 63;
  const int bm = blockIdx.x, kp = blockIdx.y;
  constexpr int KLOC = KDIM / KS;
  constexpr int NS = KLOC / 64;
  const int kbase = kp * KLOC;
  const int l16 = lane >> 4;          // 0..3
  const int rlo = lane & 15;          // 0..15
  const float* aptr0 = A + (size_t)(bm * 32 + rlo) * KDIM + kbase + l16 * 8;
  const unsigned short* bptr = B + ((size_t)((kbase >> 3) + l16) * 256 + rlo + wave * 64) * 8;

  f32x4 acc[2][4];
  #pragma unroll
  for (int mf = 0; mf < 2; ++mf)
    #pragma unroll
    for (int nf = 0; nf < 4; ++nf){
      acc[mf][nf][0] = 0.f; acc[mf][nf][1] = 0.f; acc[mf][nf][2] = 0.f; acc[mf][nf][3] = 0.f;
    }

  #pragma unroll 2
  for (int s = 0; s < NS; ++s){
    // A fragments straight from global (fp32)
    float4 af[2][2][2];
    #pragma unroll
    for (int ks = 0; ks < 2; ++ks)
      #pragma unroll
      for (int mf = 0; mf < 2; ++mf){
        const float* p = aptr0 + (size_t)mf * 16 * KDIM + s * 64 + ks * 32;
        af[ks][mf][0] = *reinterpret_cast<const float4*>(p);
        af[ks][mf][1] = *reinterpret_cast<const float4*>(p + 4);
      }
    // B fragments (bf16, contiguous 16B per lane)
    bf16x8 bfr[2][4];
    #pragma unroll
    for (int ks = 0; ks < 2; ++ks)
      #pragma unroll
      for (int nf = 0; nf < 4; ++nf)
        bfr[ks][nf] = *reinterpret_cast<const bf16x8*>(
            bptr + ((size_t)(s * 8 + ks * 4) * 256 + nf * 16) * 8);
    // convert A to bf16
    bf16x8 afr[2][2];
    #pragma unroll
    for (int ks = 0; ks < 2; ++ks)
      #pragma unroll
      for (int mf = 0; mf < 2; ++mf){
        union { bf16x8 v; unsigned short u[8]; } pk;
        pk.u[0] = f2bf(af[ks][mf][0].x); pk.u[1] = f2bf(af[ks][mf][0].y);
        pk.u[2] = f2bf(af[ks][mf][0].z); pk.u[3] = f2bf(af[ks][mf][0].w);
        pk.u[4] = f2bf(af[ks][mf][1].x); pk.u[5] = f2bf(af[ks][mf][1].y);
        pk.u[6] = f2bf(af[ks][mf][1].z); pk.u[7] = f2bf(af[ks][mf][1].w);
        afr[ks][mf] = pk.v;
      }
    #pragma unroll
    for (int ks = 0; ks < 2; ++ks)
      #pragma unroll
      for (int mf = 0; mf < 2; ++mf)
        #pragma unroll
        for (int nf = 0; nf < 4; ++nf)
          acc[mf][nf] = __builtin_amdgcn_mfma_f32_16x16x32_bf16(afr[ks][mf], bfr[ks][nf], acc[mf][nf], 0, 0, 0);
  }

  if constexpr (EPI == 0){
    unsigned short* H = reinterpret_cast<unsigned short*>(Cout);
    #pragma unroll
    for (int mf = 0; mf < 2; ++mf)
      #pragma unroll
      for (int nf = 0; nf < 4; ++nf){
        int c  = rlo + nf * 16 + wave * 64;
        int m0 = bm * 32 + mf * 16 + (l16 << 2);
        union { bf16x4 v; unsigned short u[4]; } p;
        p.u[0] = f2bf(acc[mf][nf][0]);
        p.u[1] = f2bf(acc[mf][nf][1]);
        p.u[2] = f2bf(acc[mf][nf][2]);
        p.u[3] = f2bf(acc[mf][nf][3]);
        size_t off = ((size_t)(m0 >> 3) * 256 + c) * 8 + (m0 & 7);
        *reinterpret_cast<bf16x4*>(&H[off]) = p.v;
      }
  } else {
    float* O = reinterpret_cast<float*>(Cout) + (size_t)kp * KDIM /*M==KDIM==8192*/ * 256;
    #pragma unroll
    for (int mf = 0; mf < 2; ++mf)
      #pragma unroll
      for (int nf = 0; nf < 4; ++nf){
        int c  = rlo + nf * 16 + wave * 64;
        int m0 = bm * 32 + mf * 16 + (l16 << 2);
        #pragma unroll
        for (int j = 0; j < 4; ++j)
          O[(size_t)(m0 + j) * 256 + c] = acc[mf][nf][j];
      }
  }
}

// out = relu(P0+P1+P2+P3), float4-vectorized
__global__ __launch_bounds__(256) void kreduce(const float* __restrict__ P, float* __restrict__ O){
  size_t i = (size_t)blockIdx.x * 256 + threadIdx.x;
  const float4* p0 = reinterpret_cast<const float4*>(P);
  const float4* p1 = reinterpret_cast<const float4*>(P + 2097152);
  const float4* p2 = reinterpret_cast<const float4*>(P + 4194304);
  const float4* p3 = reinterpret_cast<const float4*>(P + 6291456);
  float4 a = p0[i], b = p1[i], c = p2[i], d = p3[i];
  float4 r;
  r.x = fmaxf(a.x + b.x + c.x + d.x, 0.f);
  r.y = fmaxf(a.y + b.y + c.y + d.y, 0.f);
  r.z = fmaxf(a.z + b.z + c.z + d.z, 0.f);
  r.w = fmaxf(a.w + b.w + c.w + d.w, 0.f);
  reinterpret_cast<float4*>(O)[i] = r;
}

// ---------------- launcher ----------------

extern "C" void kernel_launch(void* const* d_in, const int* in_sizes, int n_in,
                              void* d_out, int out_size, void* d_ws, size_t ws_size,
                              hipStream_t stream) {
  const float* x   = (const float*)d_in[0];   // [8192,512]
  const float* adj = (const float*)d_in[1];   // [8192,8192]
  const float* wt  = (const float*)d_in[2];   // [256,512]
  float* out = (float*)d_out;                 // [8192,256]

  char* ws = (char*)d_ws;
  float* n2            = (float*)ws;                                    // 4 B
  float* W             = (float*)(ws + 4096);                           // 512 KB
  float* G0            = (float*)(ws + 4096 + 524288);                  // 256 KB
  float* G1            = (float*)(ws + 4096 + 524288 + 262144);         // 256 KB
  unsigned short* WT2  = (unsigned short*)(ws + 4096 + 524288 + 2*262144);   // 256 KB
  unsigned short* HT2  = (unsigned short*)(ws + 4096 + 524288 + 3*262144);   // 4 MB
  float* Cpart         = (float*)(ws + 4096 + 524288 + 3*262144 + 4194304);  // 32 MB

  hipMemsetAsync(n2, 0, 4, stream);
  hipMemsetAsync(G0, 0, 262144, stream);

  knorm<<<128, 256, 0, stream>>>(wt, n2);
  kinit<<<256, 256, 0, stream>>>(wt, n2, W);

  // 4 iterations: aggressive quintic, Muon quintic, 2 exact Bjorck steps
  const float ca[4] = { 4.2000f, 3.4445f, 1.875f, 1.875f };
  const float cb[4] = {-9.0000f, -4.7750f, -1.25f, -1.25f };
  const float cc[4] = {-6.8000f, 2.0315f, 0.375f, 0.375f };
  float* Gb[2] = {G0, G1};
  for (int it = 0; it < 4; ++it){
    float* Gc = Gb[it & 1];
    float* Gn = Gb[(it + 1) & 1];
    kgram2<<<dim3(8, 8, 8), 256, 0, stream>>>(W, Gc);
    kupdate2<<<256, 512, 0, stream>>>(W, Gc, Gn, ca[it], cb[it], cc[it], it == 3 ? 1 : 0, WT2);
  }

  // h^T (k-tiled bf16) = x @ W
  kgemm2<512, 1, 0><<<dim3(256, 1), 256, 0, stream>>>(x, WT2, (void*)HT2);
  // partials: Cpart[kp] = adj[:, kslice] @ h[kslice, :]
  kgemm2<8192, 4, 1><<<dim3(256, 4), 256, 0, stream>>>(adj, HT2, (void*)Cpart);
  // out = relu(sum partials)
  kreduce<<<2048, 256, 0, stream>>>(Cpart, out);
}

// Round 4
// 236.367 us; speedup vs baseline: 1.2721x; 1.2721x over previous
//
#include <hip/hip_runtime.h>

typedef __attribute__((ext_vector_type(8))) short bf16x8;
typedef __attribute__((ext_vector_type(4))) short bf16x4;
typedef __attribute__((ext_vector_type(4))) float f32x4;

__device__ __forceinline__ unsigned short f2bf(float x){
  unsigned u = __float_as_uint(x);
  u = (u + 0x7fffu + ((u >> 16) & 1u)) >> 16;
  return (unsigned short)u;
}

// ---------------- Bjorck (polar factor) small kernels ----------------

__global__ __launch_bounds__(256) void knorm(const float* __restrict__ wt, float* __restrict__ n2){
  int t = blockIdx.x * 256 + threadIdx.x;
  float4 v = reinterpret_cast<const float4*>(wt)[t];
  float s = v.x*v.x + v.y*v.y + v.z*v.z + v.w*v.w;
  #pragma unroll
  for (int o = 32; o > 0; o >>= 1) s += __shfl_down(s, o, 64);
  __shared__ float red[4];
  if ((threadIdx.x & 63) == 0) red[threadIdx.x >> 6] = s;
  __syncthreads();
  if (threadIdx.x == 0) atomicAdd(n2, red[0] + red[1] + red[2] + red[3]);
}

__global__ __launch_bounds__(256) void kinit(const float* __restrict__ wt, const float* __restrict__ n2,
                                             float* __restrict__ W){
  int c = blockIdx.x;
  int r = threadIdx.x;
  float s = rsqrtf(*n2) * (1.0f / 0.3f);
  W[(size_t)r * 256 + c]         = wt[(size_t)c * 512 + r] * s;
  W[(size_t)(r + 256) * 256 + c] = wt[(size_t)c * 512 + r + 256] * s;
}

// G += partial(W^T W): grid (8 j, 8 i, 8 k-parts), 32x32 tile, k-range 64
__global__ __launch_bounds__(256) void kgram2(const float* __restrict__ W, float* __restrict__ G){
  __shared__ __align__(16) float Wi[64][32];
  __shared__ __align__(16) float Wj[64][32];
  const int t = threadIdx.x;
  const int i0 = blockIdx.y * 32, j0 = blockIdx.x * 32, k0 = blockIdx.z * 64;
  const int lr = t >> 3, lc = (t & 7) * 4;
  #pragma unroll
  for (int p = 0; p < 2; ++p){
    int r = lr + p * 32;
    *reinterpret_cast<float4*>(&Wi[r][lc]) =
        *reinterpret_cast<const float4*>(&W[(size_t)(k0 + r) * 256 + i0 + lc]);
    *reinterpret_cast<float4*>(&Wj[r][lc]) =
        *reinterpret_cast<const float4*>(&W[(size_t)(k0 + r) * 256 + j0 + lc]);
  }
  __syncthreads();
  const int tx = t & 31, iy = t >> 5;
  float g0 = 0, g1 = 0, g2 = 0, g3 = 0;
  #pragma unroll 8
  for (int k = 0; k < 64; ++k){
    float wj = Wj[k][tx];
    float4 wi = *reinterpret_cast<const float4*>(&Wi[k][iy * 4]);
    g0 = fmaf(wi.x, wj, g0); g1 = fmaf(wi.y, wj, g1);
    g2 = fmaf(wi.z, wj, g2); g3 = fmaf(wi.w, wj, g3);
  }
  float* gp = &G[(size_t)(i0 + iy * 4) * 256 + j0 + tx];
  atomicAdd(gp,       g0); atomicAdd(gp + 256, g1);
  atomicAdd(gp + 512, g2); atomicAdd(gp + 768, g3);
}

// W <- ca*W + cb*(W G) + cc*(W G) G ; zeroes Gnext; last: emit k-tiled bf16 WT2
__global__ __launch_bounds__(512) void kupdate2(float* __restrict__ W, const float* __restrict__ G,
    float* __restrict__ Gnext, float ca, float cb, float cc, int last,
    unsigned short* __restrict__ WT2){
  __shared__ float wr[2][256], yl[2][256];
  const int t = threadIdx.x;
  const int c = t & 255, row = t >> 8;
  const int r = blockIdx.x * 2 + row;
  wr[row][c] = W[(size_t)r * 256 + c];
  __syncthreads();
  float y = 0;
  #pragma unroll 8
  for (int k = 0; k < 256; ++k)
    y = fmaf(wr[row][k], G[(size_t)k * 256 + c], y);
  yl[row][c] = y;
  __syncthreads();
  float d = 0;
  #pragma unroll 8
  for (int k = 0; k < 256; ++k)
    d = fmaf(yl[row][k], G[(size_t)k * 256 + c], d);
  float nw = ca * wr[row][c] + cb * y + cc * d;
  W[(size_t)r * 256 + c] = nw;
  if (r < 256) Gnext[(size_t)r * 256 + c] = 0.0f;
  if (last) WT2[((size_t)(r >> 3) * 256 + c) * 8 + (r & 7)] = f2bf(nw);
}

// ---------------- GEMM: C[M,256] = A[M,KDIM](f32) * B(bf16, k-tiled) ----------------
// B layout: element (k, c) at ((k/8)*256 + c)*8 + k%8
// EPI==0: store bf16 output in same k-tiled layout (KS must be 1)
// EPI==1: fp32 partial per kp -> Cout + kp*M*256 (plain stores)

__device__ __forceinline__ void cvt_store8(unsigned short* dst, float4 a0, float4 a1){
  union { bf16x8 v; unsigned short u[8]; } p;
  p.u[0] = f2bf(a0.x); p.u[1] = f2bf(a0.y); p.u[2] = f2bf(a0.z); p.u[3] = f2bf(a0.w);
  p.u[4] = f2bf(a1.x); p.u[5] = f2bf(a1.y); p.u[6] = f2bf(a1.z); p.u[7] = f2bf(a1.w);
  *reinterpret_cast<bf16x8*>(dst) = p.v;
}

template<int KDIM, int KS, int EPI>
__global__ __launch_bounds__(256) void kgemm(const float* __restrict__ A,
    const unsigned short* __restrict__ B, void* __restrict__ Cout){
  __shared__ unsigned short Alds[2][2048];   // 2 x [32 rows][64 cols] bf16, XOR-swizzled
  const int t = threadIdx.x;
  const int wave = t >> 6, lane = t & 63;
  const int bm = blockIdx.x, kp = blockIdx.y;
  constexpr int KLOC = KDIM / KS;
  constexpr int NS = KLOC / 64;
  const int kbase = kp * KLOC;
  const int srow = t >> 3, scol = (t & 7) * 8;
  const float* aptr = A + (size_t)(bm * 32 + srow) * KDIM + kbase + scol;
  const int swoff = (srow * 64 + scol) ^ ((srow & 7) << 3);

  f32x4 acc[2][4];
  #pragma unroll
  for (int mf = 0; mf < 2; ++mf)
    #pragma unroll
    for (int nf = 0; nf < 4; ++nf){
      acc[mf][nf][0] = 0.f; acc[mf][nf][1] = 0.f; acc[mf][nf][2] = 0.f; acc[mf][nf][3] = 0.f;
    }

  // stage step 0
  {
    float4 a0 = *reinterpret_cast<const float4*>(aptr);
    float4 a1 = *reinterpret_cast<const float4*>(aptr + 4);
    cvt_store8(&Alds[0][swoff], a0, a1);
  }
  __syncthreads();

  int cur = 0;
  for (int s = 0; s < NS; ++s){
    float4 p0, p1;
    if (s + 1 < NS){
      p0 = *reinterpret_cast<const float4*>(aptr + (s + 1) * 64);
      p1 = *reinterpret_cast<const float4*>(aptr + (s + 1) * 64 + 4);
    }
    // B fragments: lane holds 8 contiguous k at col c
    bf16x8 bfr[2][4];
    #pragma unroll
    for (int ks = 0; ks < 2; ++ks)
      #pragma unroll
      for (int nf = 0; nf < 4; ++nf){
        int c  = (lane & 15) + nf * 16 + wave * 64;
        int kb = (kbase >> 3) + s * 8 + ks * 4 + (lane >> 4);
        bfr[ks][nf] = *reinterpret_cast<const bf16x8*>(B + ((size_t)kb * 256 + c) * 8);
      }
    // A fragments from LDS (swizzled)
    bf16x8 afr[2][2];
    #pragma unroll
    for (int ks = 0; ks < 2; ++ks)
      #pragma unroll
      for (int mf = 0; mf < 2; ++mf){
        int row = (lane & 15) + mf * 16;
        int kk  = ks * 32 + ((lane >> 4) << 3);
        int off = (row * 64 + kk) ^ ((row & 7) << 3);
        afr[ks][mf] = *reinterpret_cast<const bf16x8*>(&Alds[cur][off]);
      }
    #pragma unroll
    for (int ks = 0; ks < 2; ++ks)
      #pragma unroll
      for (int mf = 0; mf < 2; ++mf)
        #pragma unroll
        for (int nf = 0; nf < 4; ++nf)
          acc[mf][nf] = __builtin_amdgcn_mfma_f32_16x16x32_bf16(afr[ks][mf], bfr[ks][nf], acc[mf][nf], 0, 0, 0);
    if (s + 1 < NS)
      cvt_store8(&Alds[cur ^ 1][swoff], p0, p1);
    __syncthreads();
    cur ^= 1;
  }

  if constexpr (EPI == 0){
    unsigned short* H = reinterpret_cast<unsigned short*>(Cout);
    #pragma unroll
    for (int mf = 0; mf < 2; ++mf)
      #pragma unroll
      for (int nf = 0; nf < 4; ++nf){
        int c  = (lane & 15) + nf * 16 + wave * 64;
        int m0 = bm * 32 + mf * 16 + ((lane >> 4) << 2);
        union { bf16x4 v; unsigned short u[4]; } p;
        p.u[0] = f2bf(acc[mf][nf][0]);
        p.u[1] = f2bf(acc[mf][nf][1]);
        p.u[2] = f2bf(acc[mf][nf][2]);
        p.u[3] = f2bf(acc[mf][nf][3]);
        size_t off = ((size_t)(m0 >> 3) * 256 + c) * 8 + (m0 & 7);
        *reinterpret_cast<bf16x4*>(&H[off]) = p.v;
      }
  } else {
    float* O = reinterpret_cast<float*>(Cout) + (size_t)kp * 8192 * 256;
    #pragma unroll
    for (int mf = 0; mf < 2; ++mf)
      #pragma unroll
      for (int nf = 0; nf < 4; ++nf){
        int c  = (lane & 15) + nf * 16 + wave * 64;
        int m0 = bm * 32 + mf * 16 + ((lane >> 4) << 2);
        #pragma unroll
        for (int j = 0; j < 4; ++j)
          O[(size_t)(m0 + j) * 256 + c] = acc[mf][nf][j];
      }
  }
}

// out = relu(sum of 8 partials), float4-vectorized
__global__ __launch_bounds__(256) void kreduce8(const float* __restrict__ P, float* __restrict__ O){
  size_t i = (size_t)blockIdx.x * 256 + threadIdx.x;
  const float4* p = reinterpret_cast<const float4*>(P);
  float4 a = p[i];
  float4 r = a;
  #pragma unroll
  for (int q = 1; q < 8; ++q){
    float4 b = p[i + (size_t)q * 524288];
    r.x += b.x; r.y += b.y; r.z += b.z; r.w += b.w;
  }
  r.x = fmaxf(r.x, 0.f); r.y = fmaxf(r.y, 0.f);
  r.z = fmaxf(r.z, 0.f); r.w = fmaxf(r.w, 0.f);
  reinterpret_cast<float4*>(O)[i] = r;
}

// ---------------- launcher ----------------

extern "C" void kernel_launch(void* const* d_in, const int* in_sizes, int n_in,
                              void* d_out, int out_size, void* d_ws, size_t ws_size,
                              hipStream_t stream) {
  const float* x   = (const float*)d_in[0];   // [8192,512]
  const float* adj = (const float*)d_in[1];   // [8192,8192]
  const float* wt  = (const float*)d_in[2];   // [256,512]
  float* out = (float*)d_out;                 // [8192,256]

  char* ws = (char*)d_ws;
  float* n2            = (float*)ws;                                    // 4 B
  float* W             = (float*)(ws + 4096);                           // 512 KB
  float* G0            = (float*)(ws + 4096 + 524288);                  // 256 KB
  float* G1            = (float*)(ws + 4096 + 524288 + 262144);         // 256 KB
  unsigned short* WT2  = (unsigned short*)(ws + 4096 + 524288 + 2*262144);   // 256 KB
  unsigned short* HT2  = (unsigned short*)(ws + 4096 + 524288 + 3*262144);   // 4 MB
  float* Cpart         = (float*)(ws + 4096 + 524288 + 3*262144 + 4194304);  // 64 MB

  hipMemsetAsync(n2, 0, 4, stream);
  hipMemsetAsync(G0, 0, 262144, stream);

  knorm<<<128, 256, 0, stream>>>(wt, n2);
  kinit<<<256, 256, 0, stream>>>(wt, n2, W);

  // 4 iterations: aggressive quintic, Muon quintic, 2 exact Bjorck steps
  const float ca[4] = { 4.2000f, 3.4445f, 1.875f, 1.875f };
  const float cb[4] = {-9.0000f, -4.7750f, -1.25f, -1.25f };
  const float cc[4] = {-6.8000f, 2.0315f, 0.375f, 0.375f };
  float* Gb[2] = {G0, G1};
  for (int it = 0; it < 4; ++it){
    float* Gc = Gb[it & 1];
    float* Gn = Gb[(it + 1) & 1];
    kgram2<<<dim3(8, 8, 8), 256, 0, stream>>>(W, Gc);
    kupdate2<<<256, 512, 0, stream>>>(W, Gc, Gn, ca[it], cb[it], cc[it], it == 3 ? 1 : 0, WT2);
  }

  // h^T (k-tiled bf16) = x @ W
  kgemm<512, 1, 0><<<dim3(256, 1), 256, 0, stream>>>(x, WT2, (void*)HT2);
  // partials: Cpart[kp] = adj[:, kslice] @ h[kslice, :]  (8 blocks/CU, full occupancy)
  kgemm<8192, 8, 1><<<dim3(256, 8), 256, 0, stream>>>(adj, HT2, (void*)Cpart);
  // out = relu(sum partials)
  kreduce8<<<2048, 256, 0, stream>>>(Cpart, out);
}

// Round 5
// 225.353 us; speedup vs baseline: 1.3343x; 1.0489x over previous
//
#include <hip/hip_runtime.h>

typedef __attribute__((ext_vector_type(8))) short bf16x8;
typedef __attribute__((ext_vector_type(4))) short bf16x4;
typedef __attribute__((ext_vector_type(4))) float f32x4;

__device__ __forceinline__ unsigned short f2bf(float x){
  unsigned u = __float_as_uint(x);
  u = (u + 0x7fffu + ((u >> 16) & 1u)) >> 16;
  return (unsigned short)u;
}

// lgkm-only barrier: orders LDS write->read across waves WITHOUT draining vmcnt
// (register-destined global prefetches stay in flight across it)
#define BARRIER() do { asm volatile("s_waitcnt lgkmcnt(0)" ::: "memory"); \
                       __builtin_amdgcn_s_barrier(); } while(0)

// ---------------- zero init (replaces hipMemsetAsync fills) ----------------
__global__ __launch_bounds__(256) void kzero(float* __restrict__ G0, float* __restrict__ n2){
  int b = blockIdx.x;
  if (b < 256) G0[b * 256 + threadIdx.x] = 0.0f;
  else if (threadIdx.x == 0) *n2 = 0.0f;
}

// ---------------- Bjorck (polar factor) small kernels ----------------

__global__ __launch_bounds__(256) void knorm(const float* __restrict__ wt, float* __restrict__ n2){
  int t = blockIdx.x * 256 + threadIdx.x;
  float4 v = reinterpret_cast<const float4*>(wt)[t];
  float s = v.x*v.x + v.y*v.y + v.z*v.z + v.w*v.w;
  #pragma unroll
  for (int o = 32; o > 0; o >>= 1) s += __shfl_down(s, o, 64);
  __shared__ float red[4];
  if ((threadIdx.x & 63) == 0) red[threadIdx.x >> 6] = s;
  __syncthreads();
  if (threadIdx.x == 0) atomicAdd(n2, red[0] + red[1] + red[2] + red[3]);
}

__global__ __launch_bounds__(256) void kinit(const float* __restrict__ wt, const float* __restrict__ n2,
                                             float* __restrict__ W){
  int c = blockIdx.x;
  int r = threadIdx.x;
  float s = rsqrtf(*n2) * (1.0f / 0.3f);
  W[(size_t)r * 256 + c]         = wt[(size_t)c * 512 + r] * s;
  W[(size_t)(r + 256) * 256 + c] = wt[(size_t)c * 512 + r + 256] * s;
}

// G += partial(W^T W): grid (8 j, 8 i, 8 k-parts), 32x32 tile, k-range 64
__global__ __launch_bounds__(256) void kgram2(const float* __restrict__ W, float* __restrict__ G){
  __shared__ __align__(16) float Wi[64][32];
  __shared__ __align__(16) float Wj[64][32];
  const int t = threadIdx.x;
  const int i0 = blockIdx.y * 32, j0 = blockIdx.x * 32, k0 = blockIdx.z * 64;
  const int lr = t >> 3, lc = (t & 7) * 4;
  #pragma unroll
  for (int p = 0; p < 2; ++p){
    int r = lr + p * 32;
    *reinterpret_cast<float4*>(&Wi[r][lc]) =
        *reinterpret_cast<const float4*>(&W[(size_t)(k0 + r) * 256 + i0 + lc]);
    *reinterpret_cast<float4*>(&Wj[r][lc]) =
        *reinterpret_cast<const float4*>(&W[(size_t)(k0 + r) * 256 + j0 + lc]);
  }
  __syncthreads();
  const int tx = t & 31, iy = t >> 5;
  float g0 = 0, g1 = 0, g2 = 0, g3 = 0;
  #pragma unroll 8
  for (int k = 0; k < 64; ++k){
    float wj = Wj[k][tx];
    float4 wi = *reinterpret_cast<const float4*>(&Wi[k][iy * 4]);
    g0 = fmaf(wi.x, wj, g0); g1 = fmaf(wi.y, wj, g1);
    g2 = fmaf(wi.z, wj, g2); g3 = fmaf(wi.w, wj, g3);
  }
  float* gp = &G[(size_t)(i0 + iy * 4) * 256 + j0 + tx];
  atomicAdd(gp,       g0); atomicAdd(gp + 256, g1);
  atomicAdd(gp + 512, g2); atomicAdd(gp + 768, g3);
}

// W <- ca*W + cb*(W G) + cc*(W G) G ; zeroes Gnext; last: emit k-tiled bf16 WT2
__global__ __launch_bounds__(512) void kupdate2(float* __restrict__ W, const float* __restrict__ G,
    float* __restrict__ Gnext, float ca, float cb, float cc, int last,
    unsigned short* __restrict__ WT2){
  __shared__ float wr[2][256], yl[2][256];
  const int t = threadIdx.x;
  const int c = t & 255, row = t >> 8;
  const int r = blockIdx.x * 2 + row;
  wr[row][c] = W[(size_t)r * 256 + c];
  __syncthreads();
  float y = 0;
  #pragma unroll 8
  for (int k = 0; k < 256; ++k)
    y = fmaf(wr[row][k], G[(size_t)k * 256 + c], y);
  yl[row][c] = y;
  __syncthreads();
  float d = 0;
  #pragma unroll 8
  for (int k = 0; k < 256; ++k)
    d = fmaf(yl[row][k], G[(size_t)k * 256 + c], d);
  float nw = ca * wr[row][c] + cb * y + cc * d;
  W[(size_t)r * 256 + c] = nw;
  if (r < 256) Gnext[(size_t)r * 256 + c] = 0.0f;
  if (last) WT2[((size_t)(r >> 3) * 256 + c) * 8 + (r & 7)] = f2bf(nw);
}

// ---------------- GEMM: C[M,256] = A[M,KDIM](f32) * B(bf16, k-tiled) ----------------
// BM=64, BK=64. 4 waves, each computing 64 rows x 64 cols (mf=4, nf=4).
// Depth-2 register A-prefetch; B loads issued BEFORE the A issue each step so the
// MFMA's vmcnt wait (FIFO) never forces the fresh HBM prefetch to retire.
// B layout: element (k, c) at ((k/8)*256 + c)*8 + k%8
// EPI==0: bf16 k-tiled output (KS must be 1)
// EPI==1: fp32 partial per kp -> Cout + kp*8192*256

__device__ __forceinline__ bf16x8 cvtpack8(float4 a, float4 b){
  union { bf16x8 v; unsigned short u[8]; } p;
  p.u[0] = f2bf(a.x); p.u[1] = f2bf(a.y); p.u[2] = f2bf(a.z); p.u[3] = f2bf(a.w);
  p.u[4] = f2bf(b.x); p.u[5] = f2bf(b.y); p.u[6] = f2bf(b.z); p.u[7] = f2bf(b.w);
  return p.v;
}

template<int KDIM, int KS, int EPI>
__global__ __launch_bounds__(256) void kgemm3(const float* __restrict__ A,
    const unsigned short* __restrict__ B, void* __restrict__ Cout){
  __shared__ unsigned short Alds[2][4096];   // 2 x [64 rows][64 cols] bf16, XOR-swizzled

  const int t = threadIdx.x;
  const int wave = t >> 6, lane = t & 63;
  const int rlo = lane & 15, l16 = lane >> 4;
  // XCD swizzle: consecutive blockIdx round-robin across 8 XCDs -> kp = id%8 pins
  // one K-slice (512KB of B) per XCD L2.
  const int kp = (KS > 1) ? (blockIdx.x % KS) : 0;
  const int bm = (KS > 1) ? (blockIdx.x / KS) : blockIdx.x;
  constexpr int KLOC = KDIM / KS;
  constexpr int NS = KLOC / 64;
  const int kbase = kp * KLOC;

  // staging: thread t covers row sr = t>>2, 16 cols at (t&3)*16
  const int sr = t >> 2;
  const float* aptr = A + (size_t)(bm * 64 + sr) * KDIM + kbase + (t & 3) * 16;
  const int wb0 = ((sr * 128 + (t & 3) * 32)      ) ^ ((sr & 7) << 4);
  const int wb1 = ((sr * 128 + (t & 3) * 32 + 16) ) ^ ((sr & 7) << 4);

  f32x4 acc[4][4];
  #pragma unroll
  for (int mf = 0; mf < 4; ++mf)
    #pragma unroll
    for (int nf = 0; nf < 4; ++nf){
      acc[mf][nf][0] = 0.f; acc[mf][nf][1] = 0.f; acc[mf][nf][2] = 0.f; acc[mf][nf][3] = 0.f;
    }

#define LOADA(P, s) { const float* p_ = aptr + (size_t)(s) * 64;                 \
    P[0] = *reinterpret_cast<const float4*>(p_);                                 \
    P[1] = *reinterpret_cast<const float4*>(p_ + 4);                             \
    P[2] = *reinterpret_cast<const float4*>(p_ + 8);                             \
    P[3] = *reinterpret_cast<const float4*>(p_ + 12); }
#define STOREA(buf, P) {                                                         \
    char* b_ = reinterpret_cast<char*>(&Alds[buf][0]);                           \
    *reinterpret_cast<bf16x8*>(b_ + wb0) = cvtpack8(P[0], P[1]);                 \
    *reinterpret_cast<bf16x8*>(b_ + wb1) = cvtpack8(P[2], P[3]); }

  float4 qA[4], qB[4];
  LOADA(qA, 0);
  LOADA(qB, 1);
  STOREA(0, qA);
  qA[0] = qB[0]; qA[1] = qB[1]; qA[2] = qB[2]; qA[3] = qB[3];
  LOADA(qB, 2);
  BARRIER();

  #pragma unroll 2
  for (int s = 0; s < NS; ++s){
    const int cur = s & 1;
    // 1) stage A(s+1) into the other buffer (vmcnt waits only the depth-2-old qA)
    if (s + 1 < NS) STOREA(cur ^ 1, qA);
    // 2) B fragment loads (L2) — issued BEFORE the new A prefetch
    bf16x8 bfr[2][4];
    #pragma unroll
    for (int ks = 0; ks < 2; ++ks)
      #pragma unroll
      for (int nf = 0; nf < 4; ++nf){
        int kb = (kbase >> 3) + s * 8 + ks * 4 + l16;
        int c  = wave * 64 + nf * 16 + rlo;
        bfr[ks][nf] = *reinterpret_cast<const bf16x8*>(B + ((size_t)kb * 256 + c) * 8);
      }
    // 3) rotate pending and issue A(s+3) (HBM, consumed 2 iterations later)
    qA[0] = qB[0]; qA[1] = qB[1]; qA[2] = qB[2]; qA[3] = qB[3];
    if (s + 3 < NS) LOADA(qB, s + 3);
    // 4) A fragments from LDS + MFMA
    #pragma unroll
    for (int ks = 0; ks < 2; ++ks){
      bf16x8 afr[4];
      #pragma unroll
      for (int mf = 0; mf < 4; ++mf){
        int off = ((mf * 16 + rlo) * 128 + ks * 64 + l16 * 16) ^ ((rlo & 7) << 4);
        afr[mf] = *reinterpret_cast<const bf16x8*>(
            reinterpret_cast<const char*>(&Alds[cur][0]) + off);
      }
      #pragma unroll
      for (int mf = 0; mf < 4; ++mf)
        #pragma unroll
        for (int nf = 0; nf < 4; ++nf)
          acc[mf][nf] = __builtin_amdgcn_mfma_f32_16x16x32_bf16(afr[mf], bfr[ks][nf], acc[mf][nf], 0, 0, 0);
    }
    BARRIER();
  }
#undef LOADA
#undef STOREA

  if constexpr (EPI == 0){
    unsigned short* H = reinterpret_cast<unsigned short*>(Cout);
    #pragma unroll
    for (int mf = 0; mf < 4; ++mf)
      #pragma unroll
      for (int nf = 0; nf < 4; ++nf){
        int c  = wave * 64 + nf * 16 + rlo;
        int m0 = bm * 64 + mf * 16 + (l16 << 2);
        union { bf16x4 v; unsigned short u[4]; } p;
        p.u[0] = f2bf(acc[mf][nf][0]);
        p.u[1] = f2bf(acc[mf][nf][1]);
        p.u[2] = f2bf(acc[mf][nf][2]);
        p.u[3] = f2bf(acc[mf][nf][3]);
        size_t off = ((size_t)(m0 >> 3) * 256 + c) * 8 + (m0 & 7);
        *reinterpret_cast<bf16x4*>(&H[off]) = p.v;
      }
  } else {
    float* O = reinterpret_cast<float*>(Cout) + (size_t)kp * 8192 * 256;
    #pragma unroll
    for (int mf = 0; mf < 4; ++mf)
      #pragma unroll
      for (int nf = 0; nf < 4; ++nf){
        int c  = wave * 64 + nf * 16 + rlo;
        int m0 = bm * 64 + mf * 16 + (l16 << 2);
        #pragma unroll
        for (int j = 0; j < 4; ++j)
          O[(size_t)(m0 + j) * 256 + c] = acc[mf][nf][j];
      }
  }
}

// out = relu(sum of 8 partials), float4-vectorized
__global__ __launch_bounds__(256) void kreduce8(const float* __restrict__ P, float* __restrict__ O){
  size_t i = (size_t)blockIdx.x * 256 + threadIdx.x;
  const float4* p = reinterpret_cast<const float4*>(P);
  float4 r = p[i];
  #pragma unroll
  for (int q = 1; q < 8; ++q){
    float4 b = p[i + (size_t)q * 524288];
    r.x += b.x; r.y += b.y; r.z += b.z; r.w += b.w;
  }
  r.x = fmaxf(r.x, 0.f); r.y = fmaxf(r.y, 0.f);
  r.z = fmaxf(r.z, 0.f); r.w = fmaxf(r.w, 0.f);
  reinterpret_cast<float4*>(O)[i] = r;
}

// ---------------- launcher ----------------

extern "C" void kernel_launch(void* const* d_in, const int* in_sizes, int n_in,
                              void* d_out, int out_size, void* d_ws, size_t ws_size,
                              hipStream_t stream) {
  const float* x   = (const float*)d_in[0];   // [8192,512]
  const float* adj = (const float*)d_in[1];   // [8192,8192]
  const float* wt  = (const float*)d_in[2];   // [256,512]
  float* out = (float*)d_out;                 // [8192,256]

  char* ws = (char*)d_ws;
  float* n2            = (float*)ws;                                    // 4 B
  float* W             = (float*)(ws + 4096);                           // 512 KB
  float* G0            = (float*)(ws + 4096 + 524288);                  // 256 KB
  float* G1            = (float*)(ws + 4096 + 524288 + 262144);         // 256 KB
  unsigned short* WT2  = (unsigned short*)(ws + 4096 + 524288 + 2*262144);   // 256 KB
  unsigned short* HT2  = (unsigned short*)(ws + 4096 + 524288 + 3*262144);   // 4 MB
  float* Cpart         = (float*)(ws + 4096 + 524288 + 3*262144 + 4194304);  // 64 MB

  kzero<<<257, 256, 0, stream>>>(G0, n2);
  knorm<<<128, 256, 0, stream>>>(wt, n2);
  kinit<<<256, 256, 0, stream>>>(wt, n2, W);

  // 4 iterations: aggressive quintic, Muon quintic, 2 exact Bjorck steps
  const float ca[4] = { 4.2000f, 3.4445f, 1.875f, 1.875f };
  const float cb[4] = {-9.0000f, -4.7750f, -1.25f, -1.25f };
  const float cc[4] = {-6.8000f, 2.0315f, 0.375f, 0.375f };
  float* Gb[2] = {G0, G1};
  for (int it = 0; it < 4; ++it){
    float* Gc = Gb[it & 1];
    float* Gn = Gb[(it + 1) & 1];
    kgram2<<<dim3(8, 8, 8), 256, 0, stream>>>(W, Gc);
    kupdate2<<<256, 512, 0, stream>>>(W, Gc, Gn, ca[it], cb[it], cc[it], it == 3 ? 1 : 0, WT2);
  }

  // h^T (k-tiled bf16) = x @ W   (M=8192 -> 128 blocks of BM=64)
  kgemm3<512, 1, 0><<<128, 256, 0, stream>>>(x, WT2, (void*)HT2);
  // partials: Cpart[kp] = adj[:, kslice] @ h[kslice, :]  (128 M-tiles x 8 kp)
  kgemm3<8192, 8, 1><<<1024, 256, 0, stream>>>(adj, HT2, (void*)Cpart);
  // out = relu(sum partials)
  kreduce8<<<2048, 256, 0, stream>>>(Cpart, out);
}